// Round 19
// baseline (2119.844 us; speedup 1.0000x reference)
//
#include <hip/hip_runtime.h>
#include <cstddef>

// Problem constants
constexpr int B = 8;
constexpr int N = 16384;
constexpr int P = 1024;       // NPOINT
constexpr int S = 32;         // MAX_SAMPLES
constexpr int NSAMP = B * P * S;   // 262144
constexpr float EPS = 1e-5f;
constexpr float INV_N = 1.0f / 262144.0f;

typedef float v2f __attribute__((ext_vector_type(2)));

// Workspace layout (bytes)
//   [0 .. 1MiB)        gidx   (B*P*S int32)
//   [1MiB .. +4KiB)    stats  (float[992] used)
//   [+ .. +64MiB)      a1     (64  x NSAMP f32)   } only if ws_size permits
//   [+ .. +128MiB)     a2     (128 x NSAMP f32)   }
constexpr int ST_S1   = 0;    // 9   input sums
constexpr int ST_S2   = 9;    // 81  input second moments (full 9x9)
constexpr int ST_SUM1 = 96;   // 64  layer1 sum
constexpr int ST_SQ1  = 160;  // 64  layer1 sumsq
constexpr int ST_SUM2 = 224;  // 128 layer2 sum
constexpr int ST_SQ2  = 352;  // 128 layer2 sumsq
constexpr int ST_SC0  = 480;  // 64
constexpr int ST_SH0  = 544;  // 64
constexpr int ST_SC1  = 608;  // 64
constexpr int ST_SH1  = 672;  // 64
constexpr int ST_SC2  = 736;  // 128
constexpr int ST_SH2  = 864;  // 128

// Cooperative LDS staging (blockDim.x == 256 in all pass kernels)
#define STAGE256(dst, src, n)                                               \
  for (int i_ = threadIdx.x; i_ < (n); i_ += 256) (dst)[i_] = (src)[i_];

// ---------------------------------------------------------------------------
// u64-key DPP wave max (fps argmax).
// ---------------------------------------------------------------------------
__device__ __forceinline__ unsigned long long wave_max_key_dpp(
    unsigned long long key) {
#define DPP_STEP(ctrl)                                                      \
  {                                                                         \
    unsigned lo = (unsigned)key;                                            \
    unsigned hi = (unsigned)(key >> 32);                                    \
    unsigned lo2 = (unsigned)__builtin_amdgcn_update_dpp(                   \
        0, (int)lo, (ctrl), 0xf, 0xf, false);                               \
    unsigned hi2 = (unsigned)__builtin_amdgcn_update_dpp(                   \
        0, (int)hi, (ctrl), 0xf, 0xf, false);                               \
    unsigned long long k2 = ((unsigned long long)hi2 << 32) | lo2;          \
    if (k2 > key) key = k2;                                                 \
  }
  DPP_STEP(0x111);
  DPP_STEP(0x112);
  DPP_STEP(0x114);
  DPP_STEP(0x118);
  DPP_STEP(0x142);
  DPP_STEP(0x143);
#undef DPP_STEP
  return key;
}

// ---------------------------------------------------------------------------
// 1) Farthest point sampling — R8 structure + ASM-LOADED coordinates.
//    ROUND-18 ANALYSIS: fps = 74% of runtime; ~700 VALU instrs/wave/iter of
//    which ~400 are compiler-REMATERIALIZED coord reloads (L2-hit re-reads
//    each of the 1024 serial iterations) + their address math. Five source-
//    level anti-remat attempts failed (pins, launch_bounds, LDS caps,
//    smaller working set, LDS-served coords): LLVM may always re-execute a
//    load of __restrict__-const memory. THIS ROUND: the loads are INLINE
//    ASM — an asm result cannot be rematerialized; the allocator must keep
//    the 96 values resident (~170 live < the 256-reg budget guaranteed by
//    the 96KB LDS cap -> 1 block/CU -> 2 waves/SIMD) or spill to scratch
//    (which would show in WRITE_SIZE; pre-committed revert signal).
//    Pitfalls handled per ISA guide: explicit s_waitcnt vmcnt(0) after the
//    asm loads (compiler doesn't track asm vmcnt) + sched_barrier(0) (rule
//    #18: hipcc hoists reg-only ops past inline-asm waitcnt).
//    Loop body/math order/tie-break key byte-identical to R8 (1557us best).
// ---------------------------------------------------------------------------
__global__ __launch_bounds__(512) void fps_kernel(
    const float* __restrict__ xyz, float* __restrict__ cent) {
#pragma clang fp contract(off)
  const int b = blockIdx.x;
  const int t = threadIdx.x;           // 0..511
  const int wave = t >> 6;             // 0..7
  const float* X = xyz + (size_t)b * N * 3;

  // Occupancy limiter: 96KB forces 1 block/CU -> 256-VGPR budget.
  __shared__ float lds_force[24576];
  __shared__ unsigned long long skey[2][8];

  // ---- asm coordinate loads: slot k <-> point i = t + k*512 ----
  float xt[32], yt[32], zt[32];
#pragma unroll
  for (int k = 0; k < 32; k++) {
    const float* p = X + 3 * (t + k * 512);
    asm volatile("global_load_dword %0, %1, off"
                 : "=v"(xt[k]) : "v"(p));
    asm volatile("global_load_dword %0, %1, off offset:4"
                 : "=v"(yt[k]) : "v"(p));
    asm volatile("global_load_dword %0, %1, off offset:8"
                 : "=v"(zt[k]) : "v"(p));
  }
  asm volatile("s_waitcnt vmcnt(0)" ::: "memory");
  __builtin_amdgcn_sched_barrier(0);   // nothing crosses the wait (rule #18)

  // pack into v2f pairs: pair m = slots {2m, 2m+1}
  v2f px[16], py[16], pz[16], dist[16];
#pragma unroll
  for (int m = 0; m < 16; m++) {
    px[m] = (v2f){xt[2 * m], xt[2 * m + 1]};
    py[m] = (v2f){yt[2 * m], yt[2 * m + 1]};
    pz[m] = (v2f){zt[2 * m], zt[2 * m + 1]};
    dist[m] = (v2f){1e10f, 1e10f};
  }

  float cx = X[0], cy = X[1], cz = X[2];   // start index 0

  if (cx > 1e29f) {                        // never true; opaque to compiler
    lds_force[t] = cy;
    cz += lds_force[t ^ 1];
  }

  for (int j = 0; j < P; j++) {
    if (t == 0) {
      float* co = cent + ((size_t)b * P + j) * 3;
      co[0] = cx; co[1] = cy; co[2] = cz;
    }
    const v2f cx2 = (v2f){cx, cx};
    const v2f cy2 = (v2f){cy, cy};
    const v2f cz2 = (v2f){cz, cz};
    float best = -1.0f;
    int bk = 0;
#pragma unroll
    for (int m = 0; m < 16; m++) {
      v2f dx = px[m] - cx2;
      v2f dy = py[m] - cy2;
      v2f dz = pz[m] - cz2;
      v2f d = (dx * dx + dy * dy) + dz * dz;   // elementwise, np rounding
      v2f nd;
      nd.x = fminf(dist[m].x, d.x);
      nd.y = fminf(dist[m].y, d.y);
      dist[m] = nd;
      if (nd.x > best) { best = nd.x; bk = 2 * m; }      // ascending k order
      if (nd.y > best) { best = nd.y; bk = 2 * m + 1; }
    }
    const int bi = t + bk * 512;
    unsigned long long key =
        ((unsigned long long)__float_as_uint(best) << 32) |
        (unsigned)(16383 - bi);
    key = wave_max_key_dpp(key);
    const int buf = j & 1;
    if ((t & 63) == 63) skey[buf][wave] = key;
    __syncthreads();
    unsigned long long bkey = skey[buf][0];
#pragma unroll
    for (int w = 1; w < 8; w++) {
      unsigned long long kk = skey[buf][w];
      if (kk > bkey) bkey = kk;
    }
    const int wi = 16383 - (int)(unsigned)(bkey & 0xFFFFFFFFull);
    cx = X[3 * wi + 0];
    cy = X[3 * wi + 1];
    cz = X[3 * wi + 2];
  }
}

// ---------------------------------------------------------------------------
// 2) Ball query (unchanged).
// ---------------------------------------------------------------------------
__global__ __launch_bounds__(256) void ballq_kernel(
    const float* __restrict__ xyz, const float* __restrict__ cent,
    int* __restrict__ gidx) {
#pragma clang fp contract(off)
  const int wid = (blockIdx.x * 256 + threadIdx.x) >> 6;
  const int lane = threadIdx.x & 63;
  const int b = wid >> 10;
  const float* X = xyz + (size_t)b * N * 3;
  const float* c = cent + (size_t)wid * 3;
  const float cx = c[0], cy = c[1], cz = c[2];
  const float cc = (cx * cx + cy * cy) + cz * cz;
  int* g = gidx + (size_t)wid * S;
  const float r2 = 0.2f * 0.2f;

  int cnt = 0;
  for (int base = 0; base < N; base += 64) {
    const int i = base + lane;
    float x = X[3 * i + 0], y = X[3 * i + 1], z = X[3 * i + 2];
    float xx = (x * x + y * y) + z * z;
    float dt = (cx * x + cy * y) + cz * z;
    float d2 = (cc - 2.0f * dt) + xx;
    bool inr = d2 < r2;
    unsigned long long m = __ballot(inr);
    if (inr) {
      int pos = cnt + (int)__popcll(m & ((1ull << lane) - 1ull));
      if (pos < S) g[pos] = i;
    }
    cnt += (int)__popcll(m);
    if (cnt >= S) break;
  }
}

// ---------------------------------------------------------------------------
// Gather one sample's 9 input channels
// ---------------------------------------------------------------------------
__device__ __forceinline__ void load_x(
    const float* __restrict__ xyz, const float* __restrict__ points,
    const float* __restrict__ cent, const int* __restrict__ gidx,
    int sample, float x[9]) {
  const int grp = sample >> 5;          // b*P+p
  const int b = grp >> 10;
  const int idx = gidx[sample];
  const float* Xp = xyz + ((size_t)b * N + idx) * 3;
  const float* Pp = points + ((size_t)b * N + idx) * 6;
  const float* C = cent + (size_t)grp * 3;
  x[0] = Xp[0] - C[0];
  x[1] = Xp[1] - C[1];
  x[2] = Xp[2] - C[2];
  x[3] = Pp[0]; x[4] = Pp[1]; x[5] = Pp[2];
  x[6] = Pp[3]; x[7] = Pp[4]; x[8] = Pp[5];
}

// ---------------------------------------------------------------------------
// 3) Input moments (unchanged).
// ---------------------------------------------------------------------------
__global__ __launch_bounds__(256) void moments_kernel(
    const float* __restrict__ xyz, const float* __restrict__ points,
    const float* __restrict__ cent, const int* __restrict__ gidx,
    float* __restrict__ stats) {
  const int tid = blockIdx.x * 256 + threadIdx.x;   // 8192 threads
  float S1[9], S2[81];
#pragma unroll
  for (int c = 0; c < 9; c++) S1[c] = 0.f;
#pragma unroll
  for (int k = 0; k < 81; k++) S2[k] = 0.f;

  for (int smp = tid; smp < NSAMP; smp += 8192) {
    float x[9];
    load_x(xyz, points, cent, gidx, smp, x);
#pragma unroll
    for (int c = 0; c < 9; c++) {
      S1[c] += x[c];
#pragma unroll
      for (int d = 0; d < 9; d++) S2[c * 9 + d] = fmaf(x[c], x[d], S2[c * 9 + d]);
    }
  }
  const int lane = threadIdx.x & 63;
#pragma unroll
  for (int c = 0; c < 9; c++) {
#pragma unroll
    for (int m = 1; m < 64; m <<= 1) S1[c] += __shfl_xor(S1[c], m, 64);
  }
#pragma unroll
  for (int k = 0; k < 81; k++) {
#pragma unroll
    for (int m = 1; m < 64; m <<= 1) S2[k] += __shfl_xor(S2[k], m, 64);
  }
  if (lane == 0) {
#pragma unroll
    for (int c = 0; c < 9; c++) atomicAdd(&stats[ST_S1 + c], S1[c]);
#pragma unroll
    for (int k = 0; k < 81; k++) atomicAdd(&stats[ST_S2 + k], S2[k]);
  }
}

__global__ void finalize0_kernel(float* __restrict__ stats,
                                 const float* __restrict__ w0,
                                 const float* __restrict__ b0,
                                 const float* __restrict__ g0,
                                 const float* __restrict__ be0) {
  const int o = threadIdx.x;   // 64
  float w[9];
#pragma unroll
  for (int c = 0; c < 9; c++) w[c] = w0[o * 9 + c];
  float dot = 0.f;
#pragma unroll
  for (int c = 0; c < 9; c++) dot += w[c] * stats[ST_S1 + c];
  float quad = 0.f;
#pragma unroll
  for (int c = 0; c < 9; c++)
#pragma unroll
    for (int d = 0; d < 9; d++) quad += w[c] * w[d] * stats[ST_S2 + c * 9 + d];
  const float bb = b0[o];
  const float mean = dot * INV_N + bb;
  const float Ey2 = (quad + 2.0f * bb * dot) * INV_N + bb * bb;
  const float var = Ey2 - mean * mean;
  const float sc = g0[o] / sqrtf(var + EPS);
  stats[ST_SC0 + o] = sc;
  stats[ST_SH0 + o] = be0[o] - mean * sc;
}

// ---------------------------------------------------------------------------
// LDS-resident helpers (R14-proven single-sample shape, ~100 VGPR).
// ---------------------------------------------------------------------------
__device__ __forceinline__ void compute_h0_l(
    const float x[9], const float* lw0, const float* lb0,
    const float* lsc0, const float* lsh0, float h0[64]) {
#pragma unroll
  for (int o = 0; o < 64; o++) {
    float a = lb0[o];
#pragma unroll
    for (int c = 0; c < 9; c++) a = fmaf(lw0[o * 9 + c], x[c], a);
    h0[o] = fmaxf(fmaf(a, lsc0[o], lsh0[o]), 0.0f);
  }
}

__device__ __forceinline__ float dot64_l(const float* lwrow, const float h[64],
                                         float a) {
  const float4* wr = (const float4*)lwrow;
#pragma unroll
  for (int c4 = 0; c4 < 16; c4++) {
    const float4 wv = wr[c4];
    a = fmaf(wv.x, h[4 * c4 + 0], a);
    a = fmaf(wv.y, h[4 * c4 + 1], a);
    a = fmaf(wv.z, h[4 * c4 + 2], a);
    a = fmaf(wv.w, h[4 * c4 + 3], a);
  }
  return a;
}

__device__ __forceinline__ void compute_h1_l(
    const float h0[64], const float* lw1, const float* lb1,
    const float* lsc1, const float* lsh1, float h1[64]) {
#pragma unroll
  for (int o = 0; o < 64; o++) {
    float a = dot64_l(&lw1[o * 64], h0, lb1[o]);
    h1[o] = fmaxf(fmaf(a, lsc1[o], lsh1[o]), 0.0f);
  }
}

// ---------------------------------------------------------------------------
// 4) pass2 — R14 structure; optional a1 store (bit-identical values).
// ---------------------------------------------------------------------------
template <bool CACHE>
__global__ __launch_bounds__(256) void pass2_t(
    const float* __restrict__ xyz, const float* __restrict__ points,
    const float* __restrict__ cent, const int* __restrict__ gidx,
    const float* __restrict__ w0, const float* __restrict__ b0,
    const float* __restrict__ w1, const float* __restrict__ b1,
    float* __restrict__ stats, float* __restrict__ a1buf) {
  __shared__ __attribute__((aligned(16))) float lw1[4096];
  __shared__ float lw0[576], lb0v[64], lsc0[64], lsh0[64], lb1v[64];
  __shared__ float ssum[4][64], ssq[4][64];
  STAGE256(lw1, w1, 4096)
  STAGE256(lw0, w0, 576)
  STAGE256(lb0v, b0, 64)
  STAGE256(lsc0, stats + ST_SC0, 64)
  STAGE256(lsh0, stats + ST_SH0, 64)
  STAGE256(lb1v, b1, 64)
  __syncthreads();

  const int tid = blockIdx.x * 256 + threadIdx.x;
  float x[9];
  load_x(xyz, points, cent, gidx, tid, x);
  float h0[64];
  compute_h0_l(x, lw0, lb0v, lsc0, lsh0, h0);

  const int wv = threadIdx.x >> 6, lane = threadIdx.x & 63;
#pragma unroll 1
  for (int o = 0; o < 64; o++) {
    float a = dot64_l(&lw1[o * 64], h0, lb1v[o]);
    if (CACHE) a1buf[(size_t)o * NSAMP + tid] = a;   // coalesced per-o
    float s = a, q = a * a;
#pragma unroll
    for (int m = 1; m < 64; m <<= 1) {
      s += __shfl_xor(s, m, 64);
      q += __shfl_xor(q, m, 64);
    }
    if (lane == 0) { ssum[wv][o] = s; ssq[wv][o] = q; }
  }
  __syncthreads();
  if (threadIdx.x < 64) {
    const int o = threadIdx.x;
    float s = ssum[0][o] + ssum[1][o] + ssum[2][o] + ssum[3][o];
    float q = ssq[0][o] + ssq[1][o] + ssq[2][o] + ssq[3][o];
    atomicAdd(&stats[ST_SUM1 + o], s);
    atomicAdd(&stats[ST_SQ1 + o], q);
  }
}

__global__ void finalize1_kernel(float* __restrict__ stats,
                                 const float* __restrict__ g1,
                                 const float* __restrict__ be1) {
  const int o = threadIdx.x;   // 64
  const float mean = stats[ST_SUM1 + o] * INV_N;
  const float var = stats[ST_SQ1 + o] * INV_N - mean * mean;
  const float sc = g1[o] / sqrtf(var + EPS);
  stats[ST_SC1 + o] = sc;
  stats[ST_SH1 + o] = be1[o] - mean * sc;
}

// ---------------------------------------------------------------------------
// 5a) pass3 fallback — R14 exact (full recompute).
// ---------------------------------------------------------------------------
__global__ __launch_bounds__(256) void pass3_kernel(
    const float* __restrict__ xyz, const float* __restrict__ points,
    const float* __restrict__ cent, const int* __restrict__ gidx,
    const float* __restrict__ w0, const float* __restrict__ b0,
    const float* __restrict__ w1, const float* __restrict__ b1,
    const float* __restrict__ w2, const float* __restrict__ b2,
    float* __restrict__ stats) {
  __shared__ __attribute__((aligned(16))) float lw1[4096];
  __shared__ __attribute__((aligned(16))) float lw2[8192];
  __shared__ float lw0[576], lb0v[64], lsc0[64], lsh0[64];
  __shared__ float lb1v[64], lsc1[64], lsh1[64], lb2v[128];
  __shared__ float ssum[4][128], ssq[4][128];
  STAGE256(lw1, w1, 4096)
  STAGE256(lw2, w2, 8192)
  STAGE256(lw0, w0, 576)
  STAGE256(lb0v, b0, 64)
  STAGE256(lsc0, stats + ST_SC0, 64)
  STAGE256(lsh0, stats + ST_SH0, 64)
  STAGE256(lb1v, b1, 64)
  STAGE256(lsc1, stats + ST_SC1, 64)
  STAGE256(lsh1, stats + ST_SH1, 64)
  STAGE256(lb2v, b2, 128)
  __syncthreads();

  const int tid = blockIdx.x * 256 + threadIdx.x;
  float x[9];
  load_x(xyz, points, cent, gidx, tid, x);
  float h0[64];
  compute_h0_l(x, lw0, lb0v, lsc0, lsh0, h0);
  float h1[64];
  compute_h1_l(h0, lw1, lb1v, lsc1, lsh1, h1);

  const int wv = threadIdx.x >> 6, lane = threadIdx.x & 63;
#pragma unroll 1
  for (int o = 0; o < 128; o++) {
    float a = dot64_l(&lw2[o * 64], h1, lb2v[o]);
    float s = a, q = a * a;
#pragma unroll
    for (int m = 1; m < 64; m <<= 1) {
      s += __shfl_xor(s, m, 64);
      q += __shfl_xor(q, m, 64);
    }
    if (lane == 0) { ssum[wv][o] = s; ssq[wv][o] = q; }
  }
  __syncthreads();
  if (threadIdx.x < 128) {
    const int o = threadIdx.x;
    float s = ssum[0][o] + ssum[1][o] + ssum[2][o] + ssum[3][o];
    float q = ssq[0][o] + ssq[1][o] + ssq[2][o] + ssq[3][o];
    atomicAdd(&stats[ST_SUM2 + o], s);
    atomicAdd(&stats[ST_SQ2 + o], q);
  }
}

// ---------------------------------------------------------------------------
// 5b) pass3 cache path — h1 from a1 (skips L0+L1 recompute), stores a2.
// ---------------------------------------------------------------------------
__global__ __launch_bounds__(256) void pass3_cache(
    const float* __restrict__ a1buf, const float* __restrict__ w2,
    const float* __restrict__ b2, float* __restrict__ stats,
    float* __restrict__ a2buf) {
  __shared__ __attribute__((aligned(16))) float lw2[8192];
  __shared__ float lsc1[64], lsh1[64], lb2v[128];
  __shared__ float ssum[4][128], ssq[4][128];
  STAGE256(lw2, w2, 8192)
  STAGE256(lsc1, stats + ST_SC1, 64)
  STAGE256(lsh1, stats + ST_SH1, 64)
  STAGE256(lb2v, b2, 128)
  __syncthreads();

  const int tid = blockIdx.x * 256 + threadIdx.x;
  float h1[64];
#pragma unroll
  for (int o = 0; o < 64; o++) {
    const float a = a1buf[(size_t)o * NSAMP + tid];    // coalesced
    h1[o] = fmaxf(fmaf(a, lsc1[o], lsh1[o]), 0.0f);
  }

  const int wv = threadIdx.x >> 6, lane = threadIdx.x & 63;
#pragma unroll 1
  for (int o = 0; o < 128; o++) {
    float a = dot64_l(&lw2[o * 64], h1, lb2v[o]);
    a2buf[(size_t)o * NSAMP + tid] = a;                // coalesced
    float s = a, q = a * a;
#pragma unroll
    for (int m = 1; m < 64; m <<= 1) {
      s += __shfl_xor(s, m, 64);
      q += __shfl_xor(q, m, 64);
    }
    if (lane == 0) { ssum[wv][o] = s; ssq[wv][o] = q; }
  }
  __syncthreads();
  if (threadIdx.x < 128) {
    const int o = threadIdx.x;
    float s = ssum[0][o] + ssum[1][o] + ssum[2][o] + ssum[3][o];
    float q = ssq[0][o] + ssq[1][o] + ssq[2][o] + ssq[3][o];
    atomicAdd(&stats[ST_SUM2 + o], s);
    atomicAdd(&stats[ST_SQ2 + o], q);
  }
}

__global__ void finalize2_kernel(float* __restrict__ stats,
                                 const float* __restrict__ g2,
                                 const float* __restrict__ be2) {
  const int o = threadIdx.x;   // 128
  const float mean = stats[ST_SUM2 + o] * INV_N;
  const float var = stats[ST_SQ2 + o] * INV_N - mean * mean;
  const float sc = g2[o] / sqrtf(var + EPS);
  stats[ST_SC2 + o] = sc;
  stats[ST_SH2 + o] = be2[o] - mean * sc;
}

// ---------------------------------------------------------------------------
// 6a) pass4 fallback — R14 exact (full recompute + half-wave max).
// ---------------------------------------------------------------------------
__global__ __launch_bounds__(256) void pass4_kernel(
    const float* __restrict__ xyz, const float* __restrict__ points,
    const float* __restrict__ cent, const int* __restrict__ gidx,
    const float* __restrict__ w0, const float* __restrict__ b0,
    const float* __restrict__ w1, const float* __restrict__ b1,
    const float* __restrict__ w2, const float* __restrict__ b2,
    const float* __restrict__ stats, float* __restrict__ outnp) {
  __shared__ __attribute__((aligned(16))) float lw1[4096];
  __shared__ __attribute__((aligned(16))) float lw2[8192];
  __shared__ float lw0[576], lb0v[64], lsc0[64], lsh0[64];
  __shared__ float lb1v[64], lsc1[64], lsh1[64];
  __shared__ float lb2v[128], lsc2[128], lsh2[128];
  STAGE256(lw1, w1, 4096)
  STAGE256(lw2, w2, 8192)
  STAGE256(lw0, w0, 576)
  STAGE256(lb0v, b0, 64)
  STAGE256(lsc0, stats + ST_SC0, 64)
  STAGE256(lsh0, stats + ST_SH0, 64)
  STAGE256(lb1v, b1, 64)
  STAGE256(lsc1, stats + ST_SC1, 64)
  STAGE256(lsh1, stats + ST_SH1, 64)
  STAGE256(lb2v, b2, 128)
  STAGE256(lsc2, stats + ST_SC2, 128)
  STAGE256(lsh2, stats + ST_SH2, 128)
  __syncthreads();

  const int wid = (blockIdx.x * 256 + threadIdx.x) >> 6;  // 0..4095
  const int lane = threadIdx.x & 63;
  const int grp = wid * 2 + (lane >> 5);                  // 0..8191
  const int s = lane & 31;
  const int sample = grp * 32 + s;

  float x[9];
  load_x(xyz, points, cent, gidx, sample, x);
  float h0[64];
  compute_h0_l(x, lw0, lb0v, lsc0, lsh0, h0);
  float h1[64];
  compute_h1_l(h0, lw1, lb1v, lsc1, lsh1, h1);

#pragma unroll 1
  for (int o = 0; o < 128; o++) {
    float a = dot64_l(&lw2[o * 64], h1, lb2v[o]);
    float v = fmaxf(fmaf(a, lsc2[o], lsh2[o]), 0.0f);
#pragma unroll
    for (int m = 1; m < 32; m <<= 1) v = fmaxf(v, __shfl_xor(v, m, 64));
    if ((lane & 31) == 0) outnp[(size_t)grp * 128 + o] = v;
  }
}

// ---------------------------------------------------------------------------
// 6b) pass4 cache path — pure stream: read a2, BN2+ReLU, 32-lane max, write.
// ---------------------------------------------------------------------------
__global__ __launch_bounds__(256) void pass4_cache(
    const float* __restrict__ a2buf, const float* __restrict__ stats,
    float* __restrict__ outnp) {
  __shared__ float lsc2[128], lsh2[128];
  STAGE256(lsc2, stats + ST_SC2, 128)
  STAGE256(lsh2, stats + ST_SH2, 128)
  __syncthreads();

  const int tid = blockIdx.x * 256 + threadIdx.x;         // == sample
  const int lane = threadIdx.x & 63;
  const int grp = tid >> 5;

#pragma unroll 1
  for (int o = 0; o < 128; o++) {
    const float a = a2buf[(size_t)o * NSAMP + tid];       // coalesced
    float v = fmaxf(fmaf(a, lsc2[o], lsh2[o]), 0.0f);
#pragma unroll
    for (int m = 1; m < 32; m <<= 1) v = fmaxf(v, __shfl_xor(v, m, 64));
    if ((lane & 31) == 0) outnp[(size_t)grp * 128 + o] = v;
  }
}

// ---------------------------------------------------------------------------
extern "C" void kernel_launch(void* const* d_in, const int* in_sizes, int n_in,
                              void* d_out, int out_size, void* d_ws,
                              size_t ws_size, hipStream_t stream) {
  const float* xyz = (const float*)d_in[0];
  const float* points = (const float*)d_in[1];
  const float* w0 = (const float*)d_in[2];
  const float* b0 = (const float*)d_in[3];
  const float* g0 = (const float*)d_in[4];
  const float* be0 = (const float*)d_in[5];
  const float* w1 = (const float*)d_in[6];
  const float* b1 = (const float*)d_in[7];
  const float* g1 = (const float*)d_in[8];
  const float* be1 = (const float*)d_in[9];
  const float* w2 = (const float*)d_in[10];
  const float* b2 = (const float*)d_in[11];
  const float* g2 = (const float*)d_in[12];
  const float* be2 = (const float*)d_in[13];

  float* out = (float*)d_out;
  float* cent = out;                    // (B,P,3)
  float* outnp = out + B * P * 3;       // (B,P,128)

  const size_t GIDX_BYTES = (size_t)NSAMP * sizeof(int);      // 1 MiB
  const size_t STATS_BYTES = 4096;
  const size_t A1_BYTES = (size_t)64 * NSAMP * sizeof(float);   // 64 MiB
  const size_t A2_BYTES = (size_t)128 * NSAMP * sizeof(float);  // 128 MiB
  if (ws_size < GIDX_BYTES + STATS_BYTES) return;             // defensive
  int* gidx = (int*)d_ws;
  float* stats = (float*)((char*)d_ws + GIDX_BYTES);
  float* a1buf = (float*)((char*)d_ws + GIDX_BYTES + STATS_BYTES);
  float* a2buf = a1buf + (size_t)64 * NSAMP;
  const bool cache =
      ws_size >= GIDX_BYTES + STATS_BYTES + A1_BYTES + A2_BYTES;

  hipMemsetAsync(d_ws, 0, GIDX_BYTES + STATS_BYTES, stream);

  fps_kernel<<<B, 512, 0, stream>>>(xyz, cent);
  ballq_kernel<<<(B * P) / 4, 256, 0, stream>>>(xyz, cent, gidx);
  moments_kernel<<<32, 256, 0, stream>>>(xyz, points, cent, gidx, stats);
  finalize0_kernel<<<1, 64, 0, stream>>>(stats, w0, b0, g0, be0);
  if (cache) {
    pass2_t<true><<<NSAMP / 256, 256, 0, stream>>>(
        xyz, points, cent, gidx, w0, b0, w1, b1, stats, a1buf);
    finalize1_kernel<<<1, 64, 0, stream>>>(stats, g1, be1);
    pass3_cache<<<NSAMP / 256, 256, 0, stream>>>(a1buf, w2, b2, stats, a2buf);
    finalize2_kernel<<<1, 128, 0, stream>>>(stats, g2, be2);
    pass4_cache<<<NSAMP / 256, 256, 0, stream>>>(a2buf, stats, outnp);
  } else {
    pass2_t<false><<<NSAMP / 256, 256, 0, stream>>>(
        xyz, points, cent, gidx, w0, b0, w1, b1, stats, a1buf);
    finalize1_kernel<<<1, 64, 0, stream>>>(stats, g1, be1);
    pass3_kernel<<<NSAMP / 256, 256, 0, stream>>>(xyz, points, cent, gidx,
                                                  w0, b0, w1, b1, w2, b2,
                                                  stats);
    finalize2_kernel<<<1, 128, 0, stream>>>(stats, g2, be2);
    pass4_kernel<<<NSAMP / 256, 256, 0, stream>>>(xyz, points, cent, gidx,
                                                  w0, b0, w1, b1, w2, b2,
                                                  stats, outnp);
  }
}

// Round 20
// 2082.904 us; speedup vs baseline: 1.0177x; 1.0177x over previous
//
#include <hip/hip_runtime.h>
#include <cstddef>

// Problem constants
constexpr int B = 8;
constexpr int N = 16384;
constexpr int P = 1024;       // NPOINT
constexpr int S = 32;         // MAX_SAMPLES
constexpr int NSAMP = B * P * S;   // 262144
constexpr float EPS = 1e-5f;
constexpr float INV_N = 1.0f / 262144.0f;

typedef float v2f __attribute__((ext_vector_type(2)));

// Workspace layout (bytes)
//   [0 .. 1MiB)        gidx   (B*P*S int32)
//   [1MiB .. +4KiB)    stats  (float[992] used)
//   [+ .. +64MiB)      a1     (64  x NSAMP f32)   } only if ws_size permits
//   [+ .. +128MiB)     a2     (128 x NSAMP f32)   }
constexpr int ST_S1   = 0;    // 9   input sums
constexpr int ST_S2   = 9;    // 81  input second moments (full 9x9)
constexpr int ST_SUM1 = 96;   // 64  layer1 sum
constexpr int ST_SQ1  = 160;  // 64  layer1 sumsq
constexpr int ST_SUM2 = 224;  // 128 layer2 sum
constexpr int ST_SQ2  = 352;  // 128 layer2 sumsq
constexpr int ST_SC0  = 480;  // 64
constexpr int ST_SH0  = 544;  // 64
constexpr int ST_SC1  = 608;  // 64
constexpr int ST_SH1  = 672;  // 64
constexpr int ST_SC2  = 736;  // 128
constexpr int ST_SH2  = 864;  // 128

// Cooperative LDS staging (blockDim.x == 256 in all pass kernels)
#define STAGE256(dst, src, n)                                               \
  for (int i_ = threadIdx.x; i_ < (n); i_ += 256) (dst)[i_] = (src)[i_];

// ---------------------------------------------------------------------------
// u64-key DPP wave max (fps argmax).
// ---------------------------------------------------------------------------
__device__ __forceinline__ unsigned long long wave_max_key_dpp(
    unsigned long long key) {
#define DPP_STEP(ctrl)                                                      \
  {                                                                         \
    unsigned lo = (unsigned)key;                                            \
    unsigned hi = (unsigned)(key >> 32);                                    \
    unsigned lo2 = (unsigned)__builtin_amdgcn_update_dpp(                   \
        0, (int)lo, (ctrl), 0xf, 0xf, false);                               \
    unsigned hi2 = (unsigned)__builtin_amdgcn_update_dpp(                   \
        0, (int)hi, (ctrl), 0xf, 0xf, false);                               \
    unsigned long long k2 = ((unsigned long long)hi2 << 32) | lo2;          \
    if (k2 > key) key = k2;                                                 \
  }
  DPP_STEP(0x111);
  DPP_STEP(0x112);
  DPP_STEP(0x114);
  DPP_STEP(0x118);
  DPP_STEP(0x142);
  DPP_STEP(0x143);
#undef DPP_STEP
  return key;
}

// ---------------------------------------------------------------------------
// 1) Farthest point sampling — R8 loop + CONTIGUOUS-BLOCK point ownership.
//    ROUND-19 RECORD: 9 fps variants in [1557,1855]; asm loads didn't raise
//    VGPR (88) — allocator remats the pack/extract chain regardless. THIS
//    ROUND: make the remat CHEAP instead of fighting it. Thread t owns
//    points [32t, 32t+32): its 96 coords are CONSECUTIVE floats = 24
//    aligned float4 loads at base+imm offset. Per-iteration re-fetch cost
//    (if remat'd): 24 VMEM issues + 0 addr math, vs 96 issues + ~300 addr
//    instrs before. If kept resident instead: full win (~96 payload VGPRs
//    fit the 256 budget from the 96KB LDS cap -> 1 blk/CU).
//    Math ops & order byte-identical to R8; only lane<->point mapping
//    changed (cannot affect values). Tie-break exact: intra-thread
//    ascending-k = ascending global index (32t+k); key
//    (distbits<<32)|(16383-bi) -> global max-dist, then min index.
// ---------------------------------------------------------------------------
__global__ __launch_bounds__(512) void fps_kernel(
    const float* __restrict__ xyz, float* __restrict__ cent) {
#pragma clang fp contract(off)
  const int b = blockIdx.x;
  const int t = threadIdx.x;           // 0..511
  const int wave = t >> 6;             // 0..7
  const float* X = xyz + (size_t)b * N * 3;

  // Occupancy limiter: 96KB forces 1 block/CU -> 256-VGPR budget.
  __shared__ float lds_force[24576];
  __shared__ unsigned long long skey[2][8];

  // Thread t's 32 points: 96 contiguous floats, 16B-aligned (t*384).
  // Groups of 3 float4 = 4 points = 2 v2f pairs.
  const float4* F4 = (const float4*)(X + (size_t)t * 96);
  v2f px[16], py[16], pz[16], dist[16];
#pragma unroll
  for (int g = 0; g < 8; g++) {
    const float4 a = F4[3 * g + 0];    // x0 y0 z0 x1
    const float4 q = F4[3 * g + 1];    // y1 z1 x2 y2
    const float4 c = F4[3 * g + 2];    // z2 x3 y3 z3
    px[2 * g + 0] = (v2f){a.x, a.w};
    py[2 * g + 0] = (v2f){a.y, q.x};
    pz[2 * g + 0] = (v2f){a.z, q.y};
    px[2 * g + 1] = (v2f){q.z, c.y};
    py[2 * g + 1] = (v2f){q.w, c.z};
    pz[2 * g + 1] = (v2f){c.x, c.w};
    dist[2 * g + 0] = (v2f){1e10f, 1e10f};
    dist[2 * g + 1] = (v2f){1e10f, 1e10f};
  }

  float cx = X[0], cy = X[1], cz = X[2];   // start index 0

  if (cx > 1e29f) {                        // never true; opaque to compiler
    lds_force[t] = cy;
    cz += lds_force[t ^ 1];
  }

  for (int j = 0; j < P; j++) {
    if (t == 0) {
      float* co = cent + ((size_t)b * P + j) * 3;
      co[0] = cx; co[1] = cy; co[2] = cz;
    }
    const v2f cx2 = (v2f){cx, cx};
    const v2f cy2 = (v2f){cy, cy};
    const v2f cz2 = (v2f){cz, cz};
    float best = -1.0f;
    int bk = 0;
#pragma unroll
    for (int m = 0; m < 16; m++) {
      v2f dx = px[m] - cx2;
      v2f dy = py[m] - cy2;
      v2f dz = pz[m] - cz2;
      v2f d = (dx * dx + dy * dy) + dz * dz;   // elementwise, np rounding
      v2f nd;
      nd.x = fminf(dist[m].x, d.x);
      nd.y = fminf(dist[m].y, d.y);
      dist[m] = nd;
      if (nd.x > best) { best = nd.x; bk = 2 * m; }      // ascending k order
      if (nd.y > best) { best = nd.y; bk = 2 * m + 1; }
    }
    const int bi = t * 32 + bk;              // global point index
    unsigned long long key =
        ((unsigned long long)__float_as_uint(best) << 32) |
        (unsigned)(16383 - bi);
    key = wave_max_key_dpp(key);
    const int buf = j & 1;
    if ((t & 63) == 63) skey[buf][wave] = key;
    __syncthreads();
    unsigned long long bkey = skey[buf][0];
#pragma unroll
    for (int w = 1; w < 8; w++) {
      unsigned long long kk = skey[buf][w];
      if (kk > bkey) bkey = kk;
    }
    const int wi = 16383 - (int)(unsigned)(bkey & 0xFFFFFFFFull);
    cx = X[3 * wi + 0];
    cy = X[3 * wi + 1];
    cz = X[3 * wi + 2];
  }
}

// ---------------------------------------------------------------------------
// 2) Ball query (unchanged).
// ---------------------------------------------------------------------------
__global__ __launch_bounds__(256) void ballq_kernel(
    const float* __restrict__ xyz, const float* __restrict__ cent,
    int* __restrict__ gidx) {
#pragma clang fp contract(off)
  const int wid = (blockIdx.x * 256 + threadIdx.x) >> 6;
  const int lane = threadIdx.x & 63;
  const int b = wid >> 10;
  const float* X = xyz + (size_t)b * N * 3;
  const float* c = cent + (size_t)wid * 3;
  const float cx = c[0], cy = c[1], cz = c[2];
  const float cc = (cx * cx + cy * cy) + cz * cz;
  int* g = gidx + (size_t)wid * S;
  const float r2 = 0.2f * 0.2f;

  int cnt = 0;
  for (int base = 0; base < N; base += 64) {
    const int i = base + lane;
    float x = X[3 * i + 0], y = X[3 * i + 1], z = X[3 * i + 2];
    float xx = (x * x + y * y) + z * z;
    float dt = (cx * x + cy * y) + cz * z;
    float d2 = (cc - 2.0f * dt) + xx;
    bool inr = d2 < r2;
    unsigned long long m = __ballot(inr);
    if (inr) {
      int pos = cnt + (int)__popcll(m & ((1ull << lane) - 1ull));
      if (pos < S) g[pos] = i;
    }
    cnt += (int)__popcll(m);
    if (cnt >= S) break;
  }
}

// ---------------------------------------------------------------------------
// Gather one sample's 9 input channels
// ---------------------------------------------------------------------------
__device__ __forceinline__ void load_x(
    const float* __restrict__ xyz, const float* __restrict__ points,
    const float* __restrict__ cent, const int* __restrict__ gidx,
    int sample, float x[9]) {
  const int grp = sample >> 5;          // b*P+p
  const int b = grp >> 10;
  const int idx = gidx[sample];
  const float* Xp = xyz + ((size_t)b * N + idx) * 3;
  const float* Pp = points + ((size_t)b * N + idx) * 6;
  const float* C = cent + (size_t)grp * 3;
  x[0] = Xp[0] - C[0];
  x[1] = Xp[1] - C[1];
  x[2] = Xp[2] - C[2];
  x[3] = Pp[0]; x[4] = Pp[1]; x[5] = Pp[2];
  x[6] = Pp[3]; x[7] = Pp[4]; x[8] = Pp[5];
}

// ---------------------------------------------------------------------------
// 3) Input moments (unchanged).
// ---------------------------------------------------------------------------
__global__ __launch_bounds__(256) void moments_kernel(
    const float* __restrict__ xyz, const float* __restrict__ points,
    const float* __restrict__ cent, const int* __restrict__ gidx,
    float* __restrict__ stats) {
  const int tid = blockIdx.x * 256 + threadIdx.x;   // 8192 threads
  float S1[9], S2[81];
#pragma unroll
  for (int c = 0; c < 9; c++) S1[c] = 0.f;
#pragma unroll
  for (int k = 0; k < 81; k++) S2[k] = 0.f;

  for (int smp = tid; smp < NSAMP; smp += 8192) {
    float x[9];
    load_x(xyz, points, cent, gidx, smp, x);
#pragma unroll
    for (int c = 0; c < 9; c++) {
      S1[c] += x[c];
#pragma unroll
      for (int d = 0; d < 9; d++) S2[c * 9 + d] = fmaf(x[c], x[d], S2[c * 9 + d]);
    }
  }
  const int lane = threadIdx.x & 63;
#pragma unroll
  for (int c = 0; c < 9; c++) {
#pragma unroll
    for (int m = 1; m < 64; m <<= 1) S1[c] += __shfl_xor(S1[c], m, 64);
  }
#pragma unroll
  for (int k = 0; k < 81; k++) {
#pragma unroll
    for (int m = 1; m < 64; m <<= 1) S2[k] += __shfl_xor(S2[k], m, 64);
  }
  if (lane == 0) {
#pragma unroll
    for (int c = 0; c < 9; c++) atomicAdd(&stats[ST_S1 + c], S1[c]);
#pragma unroll
    for (int k = 0; k < 81; k++) atomicAdd(&stats[ST_S2 + k], S2[k]);
  }
}

__global__ void finalize0_kernel(float* __restrict__ stats,
                                 const float* __restrict__ w0,
                                 const float* __restrict__ b0,
                                 const float* __restrict__ g0,
                                 const float* __restrict__ be0) {
  const int o = threadIdx.x;   // 64
  float w[9];
#pragma unroll
  for (int c = 0; c < 9; c++) w[c] = w0[o * 9 + c];
  float dot = 0.f;
#pragma unroll
  for (int c = 0; c < 9; c++) dot += w[c] * stats[ST_S1 + c];
  float quad = 0.f;
#pragma unroll
  for (int c = 0; c < 9; c++)
#pragma unroll
    for (int d = 0; d < 9; d++) quad += w[c] * w[d] * stats[ST_S2 + c * 9 + d];
  const float bb = b0[o];
  const float mean = dot * INV_N + bb;
  const float Ey2 = (quad + 2.0f * bb * dot) * INV_N + bb * bb;
  const float var = Ey2 - mean * mean;
  const float sc = g0[o] / sqrtf(var + EPS);
  stats[ST_SC0 + o] = sc;
  stats[ST_SH0 + o] = be0[o] - mean * sc;
}

// ---------------------------------------------------------------------------
// LDS-resident helpers (R14-proven single-sample shape, ~100 VGPR).
// ---------------------------------------------------------------------------
__device__ __forceinline__ void compute_h0_l(
    const float x[9], const float* lw0, const float* lb0,
    const float* lsc0, const float* lsh0, float h0[64]) {
#pragma unroll
  for (int o = 0; o < 64; o++) {
    float a = lb0[o];
#pragma unroll
    for (int c = 0; c < 9; c++) a = fmaf(lw0[o * 9 + c], x[c], a);
    h0[o] = fmaxf(fmaf(a, lsc0[o], lsh0[o]), 0.0f);
  }
}

__device__ __forceinline__ float dot64_l(const float* lwrow, const float h[64],
                                         float a) {
  const float4* wr = (const float4*)lwrow;
#pragma unroll
  for (int c4 = 0; c4 < 16; c4++) {
    const float4 wv = wr[c4];
    a = fmaf(wv.x, h[4 * c4 + 0], a);
    a = fmaf(wv.y, h[4 * c4 + 1], a);
    a = fmaf(wv.z, h[4 * c4 + 2], a);
    a = fmaf(wv.w, h[4 * c4 + 3], a);
  }
  return a;
}

__device__ __forceinline__ void compute_h1_l(
    const float h0[64], const float* lw1, const float* lb1,
    const float* lsc1, const float* lsh1, float h1[64]) {
#pragma unroll
  for (int o = 0; o < 64; o++) {
    float a = dot64_l(&lw1[o * 64], h0, lb1[o]);
    h1[o] = fmaxf(fmaf(a, lsc1[o], lsh1[o]), 0.0f);
  }
}

// ---------------------------------------------------------------------------
// 4) pass2 — R14 structure; optional a1 store (bit-identical values).
// ---------------------------------------------------------------------------
template <bool CACHE>
__global__ __launch_bounds__(256) void pass2_t(
    const float* __restrict__ xyz, const float* __restrict__ points,
    const float* __restrict__ cent, const int* __restrict__ gidx,
    const float* __restrict__ w0, const float* __restrict__ b0,
    const float* __restrict__ w1, const float* __restrict__ b1,
    float* __restrict__ stats, float* __restrict__ a1buf) {
  __shared__ __attribute__((aligned(16))) float lw1[4096];
  __shared__ float lw0[576], lb0v[64], lsc0[64], lsh0[64], lb1v[64];
  __shared__ float ssum[4][64], ssq[4][64];
  STAGE256(lw1, w1, 4096)
  STAGE256(lw0, w0, 576)
  STAGE256(lb0v, b0, 64)
  STAGE256(lsc0, stats + ST_SC0, 64)
  STAGE256(lsh0, stats + ST_SH0, 64)
  STAGE256(lb1v, b1, 64)
  __syncthreads();

  const int tid = blockIdx.x * 256 + threadIdx.x;
  float x[9];
  load_x(xyz, points, cent, gidx, tid, x);
  float h0[64];
  compute_h0_l(x, lw0, lb0v, lsc0, lsh0, h0);

  const int wv = threadIdx.x >> 6, lane = threadIdx.x & 63;
#pragma unroll 1
  for (int o = 0; o < 64; o++) {
    float a = dot64_l(&lw1[o * 64], h0, lb1v[o]);
    if (CACHE) a1buf[(size_t)o * NSAMP + tid] = a;   // coalesced per-o
    float s = a, q = a * a;
#pragma unroll
    for (int m = 1; m < 64; m <<= 1) {
      s += __shfl_xor(s, m, 64);
      q += __shfl_xor(q, m, 64);
    }
    if (lane == 0) { ssum[wv][o] = s; ssq[wv][o] = q; }
  }
  __syncthreads();
  if (threadIdx.x < 64) {
    const int o = threadIdx.x;
    float s = ssum[0][o] + ssum[1][o] + ssum[2][o] + ssum[3][o];
    float q = ssq[0][o] + ssq[1][o] + ssq[2][o] + ssq[3][o];
    atomicAdd(&stats[ST_SUM1 + o], s);
    atomicAdd(&stats[ST_SQ1 + o], q);
  }
}

__global__ void finalize1_kernel(float* __restrict__ stats,
                                 const float* __restrict__ g1,
                                 const float* __restrict__ be1) {
  const int o = threadIdx.x;   // 64
  const float mean = stats[ST_SUM1 + o] * INV_N;
  const float var = stats[ST_SQ1 + o] * INV_N - mean * mean;
  const float sc = g1[o] / sqrtf(var + EPS);
  stats[ST_SC1 + o] = sc;
  stats[ST_SH1 + o] = be1[o] - mean * sc;
}

// ---------------------------------------------------------------------------
// 5a) pass3 fallback — R14 exact (full recompute).
// ---------------------------------------------------------------------------
__global__ __launch_bounds__(256) void pass3_kernel(
    const float* __restrict__ xyz, const float* __restrict__ points,
    const float* __restrict__ cent, const int* __restrict__ gidx,
    const float* __restrict__ w0, const float* __restrict__ b0,
    const float* __restrict__ w1, const float* __restrict__ b1,
    const float* __restrict__ w2, const float* __restrict__ b2,
    float* __restrict__ stats) {
  __shared__ __attribute__((aligned(16))) float lw1[4096];
  __shared__ __attribute__((aligned(16))) float lw2[8192];
  __shared__ float lw0[576], lb0v[64], lsc0[64], lsh0[64];
  __shared__ float lb1v[64], lsc1[64], lsh1[64], lb2v[128];
  __shared__ float ssum[4][128], ssq[4][128];
  STAGE256(lw1, w1, 4096)
  STAGE256(lw2, w2, 8192)
  STAGE256(lw0, w0, 576)
  STAGE256(lb0v, b0, 64)
  STAGE256(lsc0, stats + ST_SC0, 64)
  STAGE256(lsh0, stats + ST_SH0, 64)
  STAGE256(lb1v, b1, 64)
  STAGE256(lsc1, stats + ST_SC1, 64)
  STAGE256(lsh1, stats + ST_SH1, 64)
  STAGE256(lb2v, b2, 128)
  __syncthreads();

  const int tid = blockIdx.x * 256 + threadIdx.x;
  float x[9];
  load_x(xyz, points, cent, gidx, tid, x);
  float h0[64];
  compute_h0_l(x, lw0, lb0v, lsc0, lsh0, h0);
  float h1[64];
  compute_h1_l(h0, lw1, lb1v, lsc1, lsh1, h1);

  const int wv = threadIdx.x >> 6, lane = threadIdx.x & 63;
#pragma unroll 1
  for (int o = 0; o < 128; o++) {
    float a = dot64_l(&lw2[o * 64], h1, lb2v[o]);
    float s = a, q = a * a;
#pragma unroll
    for (int m = 1; m < 64; m <<= 1) {
      s += __shfl_xor(s, m, 64);
      q += __shfl_xor(q, m, 64);
    }
    if (lane == 0) { ssum[wv][o] = s; ssq[wv][o] = q; }
  }
  __syncthreads();
  if (threadIdx.x < 128) {
    const int o = threadIdx.x;
    float s = ssum[0][o] + ssum[1][o] + ssum[2][o] + ssum[3][o];
    float q = ssq[0][o] + ssq[1][o] + ssq[2][o] + ssq[3][o];
    atomicAdd(&stats[ST_SUM2 + o], s);
    atomicAdd(&stats[ST_SQ2 + o], q);
  }
}

// ---------------------------------------------------------------------------
// 5b) pass3 cache path — h1 from a1 (skips L0+L1 recompute), stores a2.
// ---------------------------------------------------------------------------
__global__ __launch_bounds__(256) void pass3_cache(
    const float* __restrict__ a1buf, const float* __restrict__ w2,
    const float* __restrict__ b2, float* __restrict__ stats,
    float* __restrict__ a2buf) {
  __shared__ __attribute__((aligned(16))) float lw2[8192];
  __shared__ float lsc1[64], lsh1[64], lb2v[128];
  __shared__ float ssum[4][128], ssq[4][128];
  STAGE256(lw2, w2, 8192)
  STAGE256(lsc1, stats + ST_SC1, 64)
  STAGE256(lsh1, stats + ST_SH1, 64)
  STAGE256(lb2v, b2, 128)
  __syncthreads();

  const int tid = blockIdx.x * 256 + threadIdx.x;
  float h1[64];
#pragma unroll
  for (int o = 0; o < 64; o++) {
    const float a = a1buf[(size_t)o * NSAMP + tid];    // coalesced
    h1[o] = fmaxf(fmaf(a, lsc1[o], lsh1[o]), 0.0f);
  }

  const int wv = threadIdx.x >> 6, lane = threadIdx.x & 63;
#pragma unroll 1
  for (int o = 0; o < 128; o++) {
    float a = dot64_l(&lw2[o * 64], h1, lb2v[o]);
    a2buf[(size_t)o * NSAMP + tid] = a;                // coalesced
    float s = a, q = a * a;
#pragma unroll
    for (int m = 1; m < 64; m <<= 1) {
      s += __shfl_xor(s, m, 64);
      q += __shfl_xor(q, m, 64);
    }
    if (lane == 0) { ssum[wv][o] = s; ssq[wv][o] = q; }
  }
  __syncthreads();
  if (threadIdx.x < 128) {
    const int o = threadIdx.x;
    float s = ssum[0][o] + ssum[1][o] + ssum[2][o] + ssum[3][o];
    float q = ssq[0][o] + ssq[1][o] + ssq[2][o] + ssq[3][o];
    atomicAdd(&stats[ST_SUM2 + o], s);
    atomicAdd(&stats[ST_SQ2 + o], q);
  }
}

__global__ void finalize2_kernel(float* __restrict__ stats,
                                 const float* __restrict__ g2,
                                 const float* __restrict__ be2) {
  const int o = threadIdx.x;   // 128
  const float mean = stats[ST_SUM2 + o] * INV_N;
  const float var = stats[ST_SQ2 + o] * INV_N - mean * mean;
  const float sc = g2[o] / sqrtf(var + EPS);
  stats[ST_SC2 + o] = sc;
  stats[ST_SH2 + o] = be2[o] - mean * sc;
}

// ---------------------------------------------------------------------------
// 6a) pass4 fallback — R14 exact (full recompute + half-wave max).
// ---------------------------------------------------------------------------
__global__ __launch_bounds__(256) void pass4_kernel(
    const float* __restrict__ xyz, const float* __restrict__ points,
    const float* __restrict__ cent, const int* __restrict__ gidx,
    const float* __restrict__ w0, const float* __restrict__ b0,
    const float* __restrict__ w1, const float* __restrict__ b1,
    const float* __restrict__ w2, const float* __restrict__ b2,
    const float* __restrict__ stats, float* __restrict__ outnp) {
  __shared__ __attribute__((aligned(16))) float lw1[4096];
  __shared__ __attribute__((aligned(16))) float lw2[8192];
  __shared__ float lw0[576], lb0v[64], lsc0[64], lsh0[64];
  __shared__ float lb1v[64], lsc1[64], lsh1[64];
  __shared__ float lb2v[128], lsc2[128], lsh2[128];
  STAGE256(lw1, w1, 4096)
  STAGE256(lw2, w2, 8192)
  STAGE256(lw0, w0, 576)
  STAGE256(lb0v, b0, 64)
  STAGE256(lsc0, stats + ST_SC0, 64)
  STAGE256(lsh0, stats + ST_SH0, 64)
  STAGE256(lb1v, b1, 64)
  STAGE256(lsc1, stats + ST_SC1, 64)
  STAGE256(lsh1, stats + ST_SH1, 64)
  STAGE256(lb2v, b2, 128)
  STAGE256(lsc2, stats + ST_SC2, 128)
  STAGE256(lsh2, stats + ST_SH2, 128)
  __syncthreads();

  const int wid = (blockIdx.x * 256 + threadIdx.x) >> 6;  // 0..4095
  const int lane = threadIdx.x & 63;
  const int grp = wid * 2 + (lane >> 5);                  // 0..8191
  const int s = lane & 31;
  const int sample = grp * 32 + s;

  float x[9];
  load_x(xyz, points, cent, gidx, sample, x);
  float h0[64];
  compute_h0_l(x, lw0, lb0v, lsc0, lsh0, h0);
  float h1[64];
  compute_h1_l(h0, lw1, lb1v, lsc1, lsh1, h1);

#pragma unroll 1
  for (int o = 0; o < 128; o++) {
    float a = dot64_l(&lw2[o * 64], h1, lb2v[o]);
    float v = fmaxf(fmaf(a, lsc2[o], lsh2[o]), 0.0f);
#pragma unroll
    for (int m = 1; m < 32; m <<= 1) v = fmaxf(v, __shfl_xor(v, m, 64));
    if ((lane & 31) == 0) outnp[(size_t)grp * 128 + o] = v;
  }
}

// ---------------------------------------------------------------------------
// 6b) pass4 cache path — pure stream: read a2, BN2+ReLU, 32-lane max, write.
// ---------------------------------------------------------------------------
__global__ __launch_bounds__(256) void pass4_cache(
    const float* __restrict__ a2buf, const float* __restrict__ stats,
    float* __restrict__ outnp) {
  __shared__ float lsc2[128], lsh2[128];
  STAGE256(lsc2, stats + ST_SC2, 128)
  STAGE256(lsh2, stats + ST_SH2, 128)
  __syncthreads();

  const int tid = blockIdx.x * 256 + threadIdx.x;         // == sample
  const int lane = threadIdx.x & 63;
  const int grp = tid >> 5;

#pragma unroll 1
  for (int o = 0; o < 128; o++) {
    const float a = a2buf[(size_t)o * NSAMP + tid];       // coalesced
    float v = fmaxf(fmaf(a, lsc2[o], lsh2[o]), 0.0f);
#pragma unroll
    for (int m = 1; m < 32; m <<= 1) v = fmaxf(v, __shfl_xor(v, m, 64));
    if ((lane & 31) == 0) outnp[(size_t)grp * 128 + o] = v;
  }
}

// ---------------------------------------------------------------------------
extern "C" void kernel_launch(void* const* d_in, const int* in_sizes, int n_in,
                              void* d_out, int out_size, void* d_ws,
                              size_t ws_size, hipStream_t stream) {
  const float* xyz = (const float*)d_in[0];
  const float* points = (const float*)d_in[1];
  const float* w0 = (const float*)d_in[2];
  const float* b0 = (const float*)d_in[3];
  const float* g0 = (const float*)d_in[4];
  const float* be0 = (const float*)d_in[5];
  const float* w1 = (const float*)d_in[6];
  const float* b1 = (const float*)d_in[7];
  const float* g1 = (const float*)d_in[8];
  const float* be1 = (const float*)d_in[9];
  const float* w2 = (const float*)d_in[10];
  const float* b2 = (const float*)d_in[11];
  const float* g2 = (const float*)d_in[12];
  const float* be2 = (const float*)d_in[13];

  float* out = (float*)d_out;
  float* cent = out;                    // (B,P,3)
  float* outnp = out + B * P * 3;       // (B,P,128)

  const size_t GIDX_BYTES = (size_t)NSAMP * sizeof(int);      // 1 MiB
  const size_t STATS_BYTES = 4096;
  const size_t A1_BYTES = (size_t)64 * NSAMP * sizeof(float);   // 64 MiB
  const size_t A2_BYTES = (size_t)128 * NSAMP * sizeof(float);  // 128 MiB
  if (ws_size < GIDX_BYTES + STATS_BYTES) return;             // defensive
  int* gidx = (int*)d_ws;
  float* stats = (float*)((char*)d_ws + GIDX_BYTES);
  float* a1buf = (float*)((char*)d_ws + GIDX_BYTES + STATS_BYTES);
  float* a2buf = a1buf + (size_t)64 * NSAMP;
  const bool cache =
      ws_size >= GIDX_BYTES + STATS_BYTES + A1_BYTES + A2_BYTES;

  hipMemsetAsync(d_ws, 0, GIDX_BYTES + STATS_BYTES, stream);

  fps_kernel<<<B, 512, 0, stream>>>(xyz, cent);
  ballq_kernel<<<(B * P) / 4, 256, 0, stream>>>(xyz, cent, gidx);
  moments_kernel<<<32, 256, 0, stream>>>(xyz, points, cent, gidx, stats);
  finalize0_kernel<<<1, 64, 0, stream>>>(stats, w0, b0, g0, be0);
  if (cache) {
    pass2_t<true><<<NSAMP / 256, 256, 0, stream>>>(
        xyz, points, cent, gidx, w0, b0, w1, b1, stats, a1buf);
    finalize1_kernel<<<1, 64, 0, stream>>>(stats, g1, be1);
    pass3_cache<<<NSAMP / 256, 256, 0, stream>>>(a1buf, w2, b2, stats, a2buf);
    finalize2_kernel<<<1, 128, 0, stream>>>(stats, g2, be2);
    pass4_cache<<<NSAMP / 256, 256, 0, stream>>>(a2buf, stats, outnp);
  } else {
    pass2_t<false><<<NSAMP / 256, 256, 0, stream>>>(
        xyz, points, cent, gidx, w0, b0, w1, b1, stats, a1buf);
    finalize1_kernel<<<1, 64, 0, stream>>>(stats, g1, be1);
    pass3_kernel<<<NSAMP / 256, 256, 0, stream>>>(xyz, points, cent, gidx,
                                                  w0, b0, w1, b1, w2, b2,
                                                  stats);
    finalize2_kernel<<<1, 128, 0, stream>>>(stats, g2, be2);
    pass4_kernel<<<NSAMP / 256, 256, 0, stream>>>(xyz, points, cent, gidx,
                                                  w0, b0, w1, b1, w2, b2,
                                                  stats, outnp);
  }
}

// Round 21
// 1989.768 us; speedup vs baseline: 1.0654x; 1.0468x over previous
//
#include <hip/hip_runtime.h>
#include <cstddef>

// Problem constants
constexpr int B = 8;
constexpr int N = 16384;
constexpr int P = 1024;       // NPOINT
constexpr int S = 32;         // MAX_SAMPLES
constexpr int NSAMP = B * P * S;   // 262144
constexpr float EPS = 1e-5f;
constexpr float INV_N = 1.0f / 262144.0f;

typedef float v2f __attribute__((ext_vector_type(2)));

// Workspace layout (bytes)
//   [0 .. 1MiB)        gidx   (B*P*S int32)
//   [1MiB .. +4KiB)    stats  (float[992] used)
//   [+ .. +64MiB)      a1     (64  x NSAMP f32)   } only if ws_size permits
//   [+ .. +128MiB)     a2     (128 x NSAMP f32)   }
constexpr int ST_S1   = 0;    // 9   input sums
constexpr int ST_S2   = 9;    // 81  input second moments (full 9x9)
constexpr int ST_SUM1 = 96;   // 64  layer1 sum
constexpr int ST_SQ1  = 160;  // 64  layer1 sumsq
constexpr int ST_SUM2 = 224;  // 128 layer2 sum
constexpr int ST_SQ2  = 352;  // 128 layer2 sumsq
constexpr int ST_SC0  = 480;  // 64
constexpr int ST_SH0  = 544;  // 64
constexpr int ST_SC1  = 608;  // 64
constexpr int ST_SH1  = 672;  // 64
constexpr int ST_SC2  = 736;  // 128
constexpr int ST_SH2  = 864;  // 128

// Cooperative LDS staging (blockDim.x == 256 in all pass kernels)
#define STAGE256(dst, src, n)                                               \
  for (int i_ = threadIdx.x; i_ < (n); i_ += 256) (dst)[i_] = (src)[i_];

// ---------------------------------------------------------------------------
// DPP reductions (VALU pipe — replaces ds_bpermute-based __shfl_xor chains,
// which contend with the weight ds_read_b128 broadcasts on the LDS pipe).
// Sum: row_shr 1/2/4/8 + row_bcast:15 + row_bcast:31 -> lane 63 = wave sum
// (0-inject identity OK for sums; order differs from butterfly -> rounding-
// level only; R15's measured run used these and passed, absmax 0.015625).
// Max32: shr cascade + row_bcast:15 -> lane31 = max(l0..31), lane63 =
// max(l32..63); post-ReLU values >=0 so 0-inject is a safe identity (exact).
// ---------------------------------------------------------------------------
#define DPP_F32(res, v, ctrl)                                               \
  float res = __uint_as_float((unsigned)__builtin_amdgcn_update_dpp(        \
      0, (int)__float_as_uint(v), (ctrl), 0xf, 0xf, false));

__device__ __forceinline__ float dpp_sum64(float v) {
  { DPP_F32(o_, v, 0x111) v += o_; }
  { DPP_F32(o_, v, 0x112) v += o_; }
  { DPP_F32(o_, v, 0x114) v += o_; }
  { DPP_F32(o_, v, 0x118) v += o_; }
  { DPP_F32(o_, v, 0x142) v += o_; }
  { DPP_F32(o_, v, 0x143) v += o_; }
  return v;  // lane 63 holds the wave sum
}

__device__ __forceinline__ float dpp_max32(float v) {
  { DPP_F32(o_, v, 0x111) v = fmaxf(v, o_); }
  { DPP_F32(o_, v, 0x112) v = fmaxf(v, o_); }
  { DPP_F32(o_, v, 0x114) v = fmaxf(v, o_); }
  { DPP_F32(o_, v, 0x118) v = fmaxf(v, o_); }
  { DPP_F32(o_, v, 0x142) v = fmaxf(v, o_); }
  return v;  // lane 31 = max(lanes 0..31), lane 63 = max(lanes 32..63)
}

// ---------------------------------------------------------------------------
// u64-key DPP wave max (fps argmax).
// ---------------------------------------------------------------------------
__device__ __forceinline__ unsigned long long wave_max_key_dpp(
    unsigned long long key) {
#define DPP_STEP(ctrl)                                                      \
  {                                                                         \
    unsigned lo = (unsigned)key;                                            \
    unsigned hi = (unsigned)(key >> 32);                                    \
    unsigned lo2 = (unsigned)__builtin_amdgcn_update_dpp(                   \
        0, (int)lo, (ctrl), 0xf, 0xf, false);                               \
    unsigned hi2 = (unsigned)__builtin_amdgcn_update_dpp(                   \
        0, (int)hi, (ctrl), 0xf, 0xf, false);                               \
    unsigned long long k2 = ((unsigned long long)hi2 << 32) | lo2;          \
    if (k2 > key) key = k2;                                                 \
  }
  DPP_STEP(0x111);
  DPP_STEP(0x112);
  DPP_STEP(0x114);
  DPP_STEP(0x118);
  DPP_STEP(0x142);
  DPP_STEP(0x143);
#undef DPP_STEP
  return key;
}

// ---------------------------------------------------------------------------
// 1) Farthest point sampling — R20-exact (best measured: 1541us).
//    DECLARED STRUCTURAL FLOOR (10 variants in [1541,1855]): 1024 inherently
//    serial iterations on 8 CUs (cross-CU exchange >= the VALU it saves);
//    ~80% VALU-issue on active CUs (distance+tracking+remat'd loads that no
//    source/asm construct eliminated), ~20% serial reduce tail.
// ---------------------------------------------------------------------------
__global__ __launch_bounds__(512) void fps_kernel(
    const float* __restrict__ xyz, float* __restrict__ cent) {
#pragma clang fp contract(off)
  const int b = blockIdx.x;
  const int t = threadIdx.x;           // 0..511
  const int wave = t >> 6;             // 0..7
  const float* X = xyz + (size_t)b * N * 3;

  // Occupancy limiter: 96KB forces 1 block/CU -> 256-VGPR budget.
  __shared__ float lds_force[24576];
  __shared__ unsigned long long skey[2][8];

  // Thread t's 32 points: 96 contiguous floats, 16B-aligned (t*384).
  const float4* F4 = (const float4*)(X + (size_t)t * 96);
  v2f px[16], py[16], pz[16], dist[16];
#pragma unroll
  for (int g = 0; g < 8; g++) {
    const float4 a = F4[3 * g + 0];    // x0 y0 z0 x1
    const float4 q = F4[3 * g + 1];    // y1 z1 x2 y2
    const float4 c = F4[3 * g + 2];    // z2 x3 y3 z3
    px[2 * g + 0] = (v2f){a.x, a.w};
    py[2 * g + 0] = (v2f){a.y, q.x};
    pz[2 * g + 0] = (v2f){a.z, q.y};
    px[2 * g + 1] = (v2f){q.z, c.y};
    py[2 * g + 1] = (v2f){q.w, c.z};
    pz[2 * g + 1] = (v2f){c.x, c.w};
    dist[2 * g + 0] = (v2f){1e10f, 1e10f};
    dist[2 * g + 1] = (v2f){1e10f, 1e10f};
  }

  float cx = X[0], cy = X[1], cz = X[2];   // start index 0

  if (cx > 1e29f) {                        // never true; opaque to compiler
    lds_force[t] = cy;
    cz += lds_force[t ^ 1];
  }

  for (int j = 0; j < P; j++) {
    if (t == 0) {
      float* co = cent + ((size_t)b * P + j) * 3;
      co[0] = cx; co[1] = cy; co[2] = cz;
    }
    const v2f cx2 = (v2f){cx, cx};
    const v2f cy2 = (v2f){cy, cy};
    const v2f cz2 = (v2f){cz, cz};
    float best = -1.0f;
    int bk = 0;
#pragma unroll
    for (int m = 0; m < 16; m++) {
      v2f dx = px[m] - cx2;
      v2f dy = py[m] - cy2;
      v2f dz = pz[m] - cz2;
      v2f d = (dx * dx + dy * dy) + dz * dz;   // elementwise, np rounding
      v2f nd;
      nd.x = fminf(dist[m].x, d.x);
      nd.y = fminf(dist[m].y, d.y);
      dist[m] = nd;
      if (nd.x > best) { best = nd.x; bk = 2 * m; }      // ascending k order
      if (nd.y > best) { best = nd.y; bk = 2 * m + 1; }
    }
    const int bi = t * 32 + bk;              // global point index
    unsigned long long key =
        ((unsigned long long)__float_as_uint(best) << 32) |
        (unsigned)(16383 - bi);
    key = wave_max_key_dpp(key);
    const int buf = j & 1;
    if ((t & 63) == 63) skey[buf][wave] = key;
    __syncthreads();
    unsigned long long bkey = skey[buf][0];
#pragma unroll
    for (int w = 1; w < 8; w++) {
      unsigned long long kk = skey[buf][w];
      if (kk > bkey) bkey = kk;
    }
    const int wi = 16383 - (int)(unsigned)(bkey & 0xFFFFFFFFull);
    cx = X[3 * wi + 0];
    cy = X[3 * wi + 1];
    cz = X[3 * wi + 2];
  }
}

// ---------------------------------------------------------------------------
// 2) Ball query (unchanged).
// ---------------------------------------------------------------------------
__global__ __launch_bounds__(256) void ballq_kernel(
    const float* __restrict__ xyz, const float* __restrict__ cent,
    int* __restrict__ gidx) {
#pragma clang fp contract(off)
  const int wid = (blockIdx.x * 256 + threadIdx.x) >> 6;
  const int lane = threadIdx.x & 63;
  const int b = wid >> 10;
  const float* X = xyz + (size_t)b * N * 3;
  const float* c = cent + (size_t)wid * 3;
  const float cx = c[0], cy = c[1], cz = c[2];
  const float cc = (cx * cx + cy * cy) + cz * cz;
  int* g = gidx + (size_t)wid * S;
  const float r2 = 0.2f * 0.2f;

  int cnt = 0;
  for (int base = 0; base < N; base += 64) {
    const int i = base + lane;
    float x = X[3 * i + 0], y = X[3 * i + 1], z = X[3 * i + 2];
    float xx = (x * x + y * y) + z * z;
    float dt = (cx * x + cy * y) + cz * z;
    float d2 = (cc - 2.0f * dt) + xx;
    bool inr = d2 < r2;
    unsigned long long m = __ballot(inr);
    if (inr) {
      int pos = cnt + (int)__popcll(m & ((1ull << lane) - 1ull));
      if (pos < S) g[pos] = i;
    }
    cnt += (int)__popcll(m);
    if (cnt >= S) break;
  }
}

// ---------------------------------------------------------------------------
// Gather one sample's 9 input channels
// ---------------------------------------------------------------------------
__device__ __forceinline__ void load_x(
    const float* __restrict__ xyz, const float* __restrict__ points,
    const float* __restrict__ cent, const int* __restrict__ gidx,
    int sample, float x[9]) {
  const int grp = sample >> 5;          // b*P+p
  const int b = grp >> 10;
  const int idx = gidx[sample];
  const float* Xp = xyz + ((size_t)b * N + idx) * 3;
  const float* Pp = points + ((size_t)b * N + idx) * 6;
  const float* C = cent + (size_t)grp * 3;
  x[0] = Xp[0] - C[0];
  x[1] = Xp[1] - C[1];
  x[2] = Xp[2] - C[2];
  x[3] = Pp[0]; x[4] = Pp[1]; x[5] = Pp[2];
  x[6] = Pp[3]; x[7] = Pp[4]; x[8] = Pp[5];
}

// ---------------------------------------------------------------------------
// 3) Input moments (unchanged — tiny kernel).
// ---------------------------------------------------------------------------
__global__ __launch_bounds__(256) void moments_kernel(
    const float* __restrict__ xyz, const float* __restrict__ points,
    const float* __restrict__ cent, const int* __restrict__ gidx,
    float* __restrict__ stats) {
  const int tid = blockIdx.x * 256 + threadIdx.x;   // 8192 threads
  float S1[9], S2[81];
#pragma unroll
  for (int c = 0; c < 9; c++) S1[c] = 0.f;
#pragma unroll
  for (int k = 0; k < 81; k++) S2[k] = 0.f;

  for (int smp = tid; smp < NSAMP; smp += 8192) {
    float x[9];
    load_x(xyz, points, cent, gidx, smp, x);
#pragma unroll
    for (int c = 0; c < 9; c++) {
      S1[c] += x[c];
#pragma unroll
      for (int d = 0; d < 9; d++) S2[c * 9 + d] = fmaf(x[c], x[d], S2[c * 9 + d]);
    }
  }
  const int lane = threadIdx.x & 63;
#pragma unroll
  for (int c = 0; c < 9; c++) {
#pragma unroll
    for (int m = 1; m < 64; m <<= 1) S1[c] += __shfl_xor(S1[c], m, 64);
  }
#pragma unroll
  for (int k = 0; k < 81; k++) {
#pragma unroll
    for (int m = 1; m < 64; m <<= 1) S2[k] += __shfl_xor(S2[k], m, 64);
  }
  if (lane == 0) {
#pragma unroll
    for (int c = 0; c < 9; c++) atomicAdd(&stats[ST_S1 + c], S1[c]);
#pragma unroll
    for (int k = 0; k < 81; k++) atomicAdd(&stats[ST_S2 + k], S2[k]);
  }
}

__global__ void finalize0_kernel(float* __restrict__ stats,
                                 const float* __restrict__ w0,
                                 const float* __restrict__ b0,
                                 const float* __restrict__ g0,
                                 const float* __restrict__ be0) {
  const int o = threadIdx.x;   // 64
  float w[9];
#pragma unroll
  for (int c = 0; c < 9; c++) w[c] = w0[o * 9 + c];
  float dot = 0.f;
#pragma unroll
  for (int c = 0; c < 9; c++) dot += w[c] * stats[ST_S1 + c];
  float quad = 0.f;
#pragma unroll
  for (int c = 0; c < 9; c++)
#pragma unroll
    for (int d = 0; d < 9; d++) quad += w[c] * w[d] * stats[ST_S2 + c * 9 + d];
  const float bb = b0[o];
  const float mean = dot * INV_N + bb;
  const float Ey2 = (quad + 2.0f * bb * dot) * INV_N + bb * bb;
  const float var = Ey2 - mean * mean;
  const float sc = g0[o] / sqrtf(var + EPS);
  stats[ST_SC0 + o] = sc;
  stats[ST_SH0 + o] = be0[o] - mean * sc;
}

// ---------------------------------------------------------------------------
// LDS-resident helpers (R14-proven single-sample shape, ~100 VGPR).
// ---------------------------------------------------------------------------
__device__ __forceinline__ void compute_h0_l(
    const float x[9], const float* lw0, const float* lb0,
    const float* lsc0, const float* lsh0, float h0[64]) {
#pragma unroll
  for (int o = 0; o < 64; o++) {
    float a = lb0[o];
#pragma unroll
    for (int c = 0; c < 9; c++) a = fmaf(lw0[o * 9 + c], x[c], a);
    h0[o] = fmaxf(fmaf(a, lsc0[o], lsh0[o]), 0.0f);
  }
}

__device__ __forceinline__ float dot64_l(const float* lwrow, const float h[64],
                                         float a) {
  const float4* wr = (const float4*)lwrow;
#pragma unroll
  for (int c4 = 0; c4 < 16; c4++) {
    const float4 wv = wr[c4];
    a = fmaf(wv.x, h[4 * c4 + 0], a);
    a = fmaf(wv.y, h[4 * c4 + 1], a);
    a = fmaf(wv.z, h[4 * c4 + 2], a);
    a = fmaf(wv.w, h[4 * c4 + 3], a);
  }
  return a;
}

__device__ __forceinline__ void compute_h1_l(
    const float h0[64], const float* lw1, const float* lb1,
    const float* lsc1, const float* lsh1, float h1[64]) {
#pragma unroll
  for (int o = 0; o < 64; o++) {
    float a = dot64_l(&lw1[o * 64], h0, lb1[o]);
    h1[o] = fmaxf(fmaf(a, lsc1[o], lsh1[o]), 0.0f);
  }
}

// ---------------------------------------------------------------------------
// 4) pass2 — R18 structure; stats reduce moved to DPP (VALU pipe), freeing
//    the LDS pipe for the 1024 weight ds_read_b128 broadcasts per wave.
// ---------------------------------------------------------------------------
template <bool CACHE>
__global__ __launch_bounds__(256) void pass2_t(
    const float* __restrict__ xyz, const float* __restrict__ points,
    const float* __restrict__ cent, const int* __restrict__ gidx,
    const float* __restrict__ w0, const float* __restrict__ b0,
    const float* __restrict__ w1, const float* __restrict__ b1,
    float* __restrict__ stats, float* __restrict__ a1buf) {
  __shared__ __attribute__((aligned(16))) float lw1[4096];
  __shared__ float lw0[576], lb0v[64], lsc0[64], lsh0[64], lb1v[64];
  __shared__ float ssum[4][64], ssq[4][64];
  STAGE256(lw1, w1, 4096)
  STAGE256(lw0, w0, 576)
  STAGE256(lb0v, b0, 64)
  STAGE256(lsc0, stats + ST_SC0, 64)
  STAGE256(lsh0, stats + ST_SH0, 64)
  STAGE256(lb1v, b1, 64)
  __syncthreads();

  const int tid = blockIdx.x * 256 + threadIdx.x;
  float x[9];
  load_x(xyz, points, cent, gidx, tid, x);
  float h0[64];
  compute_h0_l(x, lw0, lb0v, lsc0, lsh0, h0);

  const int wv = threadIdx.x >> 6, lane = threadIdx.x & 63;
#pragma unroll 1
  for (int o = 0; o < 64; o++) {
    float a = dot64_l(&lw1[o * 64], h0, lb1v[o]);
    if (CACHE) a1buf[(size_t)o * NSAMP + tid] = a;   // coalesced per-o
    float s = dpp_sum64(a);
    float q = dpp_sum64(a * a);
    if (lane == 63) { ssum[wv][o] = s; ssq[wv][o] = q; }
  }
  __syncthreads();
  if (threadIdx.x < 64) {
    const int o = threadIdx.x;
    float s = ssum[0][o] + ssum[1][o] + ssum[2][o] + ssum[3][o];
    float q = ssq[0][o] + ssq[1][o] + ssq[2][o] + ssq[3][o];
    atomicAdd(&stats[ST_SUM1 + o], s);
    atomicAdd(&stats[ST_SQ1 + o], q);
  }
}

__global__ void finalize1_kernel(float* __restrict__ stats,
                                 const float* __restrict__ g1,
                                 const float* __restrict__ be1) {
  const int o = threadIdx.x;   // 64
  const float mean = stats[ST_SUM1 + o] * INV_N;
  const float var = stats[ST_SQ1 + o] * INV_N - mean * mean;
  const float sc = g1[o] / sqrtf(var + EPS);
  stats[ST_SC1 + o] = sc;
  stats[ST_SH1 + o] = be1[o] - mean * sc;
}

// ---------------------------------------------------------------------------
// 5a) pass3 fallback — R14 exact (full recompute; only runs if ws too small).
// ---------------------------------------------------------------------------
__global__ __launch_bounds__(256) void pass3_kernel(
    const float* __restrict__ xyz, const float* __restrict__ points,
    const float* __restrict__ cent, const int* __restrict__ gidx,
    const float* __restrict__ w0, const float* __restrict__ b0,
    const float* __restrict__ w1, const float* __restrict__ b1,
    const float* __restrict__ w2, const float* __restrict__ b2,
    float* __restrict__ stats) {
  __shared__ __attribute__((aligned(16))) float lw1[4096];
  __shared__ __attribute__((aligned(16))) float lw2[8192];
  __shared__ float lw0[576], lb0v[64], lsc0[64], lsh0[64];
  __shared__ float lb1v[64], lsc1[64], lsh1[64], lb2v[128];
  __shared__ float ssum[4][128], ssq[4][128];
  STAGE256(lw1, w1, 4096)
  STAGE256(lw2, w2, 8192)
  STAGE256(lw0, w0, 576)
  STAGE256(lb0v, b0, 64)
  STAGE256(lsc0, stats + ST_SC0, 64)
  STAGE256(lsh0, stats + ST_SH0, 64)
  STAGE256(lb1v, b1, 64)
  STAGE256(lsc1, stats + ST_SC1, 64)
  STAGE256(lsh1, stats + ST_SH1, 64)
  STAGE256(lb2v, b2, 128)
  __syncthreads();

  const int tid = blockIdx.x * 256 + threadIdx.x;
  float x[9];
  load_x(xyz, points, cent, gidx, tid, x);
  float h0[64];
  compute_h0_l(x, lw0, lb0v, lsc0, lsh0, h0);
  float h1[64];
  compute_h1_l(h0, lw1, lb1v, lsc1, lsh1, h1);

  const int wv = threadIdx.x >> 6, lane = threadIdx.x & 63;
#pragma unroll 1
  for (int o = 0; o < 128; o++) {
    float a = dot64_l(&lw2[o * 64], h1, lb2v[o]);
    float s = a, q = a * a;
#pragma unroll
    for (int m = 1; m < 64; m <<= 1) {
      s += __shfl_xor(s, m, 64);
      q += __shfl_xor(q, m, 64);
    }
    if (lane == 0) { ssum[wv][o] = s; ssq[wv][o] = q; }
  }
  __syncthreads();
  if (threadIdx.x < 128) {
    const int o = threadIdx.x;
    float s = ssum[0][o] + ssum[1][o] + ssum[2][o] + ssum[3][o];
    float q = ssq[0][o] + ssq[1][o] + ssq[2][o] + ssq[3][o];
    atomicAdd(&stats[ST_SUM2 + o], s);
    atomicAdd(&stats[ST_SQ2 + o], q);
  }
}

// ---------------------------------------------------------------------------
// 5b) pass3 cache path — h1 from a1, stores a2; stats reduce via DPP.
// ---------------------------------------------------------------------------
__global__ __launch_bounds__(256) void pass3_cache(
    const float* __restrict__ a1buf, const float* __restrict__ w2,
    const float* __restrict__ b2, float* __restrict__ stats,
    float* __restrict__ a2buf) {
  __shared__ __attribute__((aligned(16))) float lw2[8192];
  __shared__ float lsc1[64], lsh1[64], lb2v[128];
  __shared__ float ssum[4][128], ssq[4][128];
  STAGE256(lw2, w2, 8192)
  STAGE256(lsc1, stats + ST_SC1, 64)
  STAGE256(lsh1, stats + ST_SH1, 64)
  STAGE256(lb2v, b2, 128)
  __syncthreads();

  const int tid = blockIdx.x * 256 + threadIdx.x;
  float h1[64];
#pragma unroll
  for (int o = 0; o < 64; o++) {
    const float a = a1buf[(size_t)o * NSAMP + tid];    // coalesced
    h1[o] = fmaxf(fmaf(a, lsc1[o], lsh1[o]), 0.0f);
  }

  const int wv = threadIdx.x >> 6, lane = threadIdx.x & 63;
#pragma unroll 1
  for (int o = 0; o < 128; o++) {
    float a = dot64_l(&lw2[o * 64], h1, lb2v[o]);
    a2buf[(size_t)o * NSAMP + tid] = a;                // coalesced
    float s = dpp_sum64(a);
    float q = dpp_sum64(a * a);
    if (lane == 63) { ssum[wv][o] = s; ssq[wv][o] = q; }
  }
  __syncthreads();
  if (threadIdx.x < 128) {
    const int o = threadIdx.x;
    float s = ssum[0][o] + ssum[1][o] + ssum[2][o] + ssum[3][o];
    float q = ssq[0][o] + ssq[1][o] + ssq[2][o] + ssq[3][o];
    atomicAdd(&stats[ST_SUM2 + o], s);
    atomicAdd(&stats[ST_SQ2 + o], q);
  }
}

__global__ void finalize2_kernel(float* __restrict__ stats,
                                 const float* __restrict__ g2,
                                 const float* __restrict__ be2) {
  const int o = threadIdx.x;   // 128
  const float mean = stats[ST_SUM2 + o] * INV_N;
  const float var = stats[ST_SQ2 + o] * INV_N - mean * mean;
  const float sc = g2[o] / sqrtf(var + EPS);
  stats[ST_SC2 + o] = sc;
  stats[ST_SH2 + o] = be2[o] - mean * sc;
}

// ---------------------------------------------------------------------------
// 6a) pass4 fallback — R14 exact (only runs if ws too small).
// ---------------------------------------------------------------------------
__global__ __launch_bounds__(256) void pass4_kernel(
    const float* __restrict__ xyz, const float* __restrict__ points,
    const float* __restrict__ cent, const int* __restrict__ gidx,
    const float* __restrict__ w0, const float* __restrict__ b0,
    const float* __restrict__ w1, const float* __restrict__ b1,
    const float* __restrict__ w2, const float* __restrict__ b2,
    const float* __restrict__ stats, float* __restrict__ outnp) {
  __shared__ __attribute__((aligned(16))) float lw1[4096];
  __shared__ __attribute__((aligned(16))) float lw2[8192];
  __shared__ float lw0[576], lb0v[64], lsc0[64], lsh0[64];
  __shared__ float lb1v[64], lsc1[64], lsh1[64];
  __shared__ float lb2v[128], lsc2[128], lsh2[128];
  STAGE256(lw1, w1, 4096)
  STAGE256(lw2, w2, 8192)
  STAGE256(lw0, w0, 576)
  STAGE256(lb0v, b0, 64)
  STAGE256(lsc0, stats + ST_SC0, 64)
  STAGE256(lsh0, stats + ST_SH0, 64)
  STAGE256(lb1v, b1, 64)
  STAGE256(lsc1, stats + ST_SC1, 64)
  STAGE256(lsh1, stats + ST_SH1, 64)
  STAGE256(lb2v, b2, 128)
  STAGE256(lsc2, stats + ST_SC2, 128)
  STAGE256(lsh2, stats + ST_SH2, 128)
  __syncthreads();

  const int wid = (blockIdx.x * 256 + threadIdx.x) >> 6;  // 0..4095
  const int lane = threadIdx.x & 63;
  const int grp = wid * 2 + (lane >> 5);                  // 0..8191
  const int s = lane & 31;
  const int sample = grp * 32 + s;

  float x[9];
  load_x(xyz, points, cent, gidx, sample, x);
  float h0[64];
  compute_h0_l(x, lw0, lb0v, lsc0, lsh0, h0);
  float h1[64];
  compute_h1_l(h0, lw1, lb1v, lsc1, lsh1, h1);

#pragma unroll 1
  for (int o = 0; o < 128; o++) {
    float a = dot64_l(&lw2[o * 64], h1, lb2v[o]);
    float v = fmaxf(fmaf(a, lsc2[o], lsh2[o]), 0.0f);
#pragma unroll
    for (int m = 1; m < 32; m <<= 1) v = fmaxf(v, __shfl_xor(v, m, 64));
    if ((lane & 31) == 0) outnp[(size_t)grp * 128 + o] = v;
  }
}

// ---------------------------------------------------------------------------
// 6b) pass4 cache path — stream a2, BN2+ReLU, DPP 32-lane max, write.
//     lane31 writes the even group, lane63 the odd group (exact max).
// ---------------------------------------------------------------------------
__global__ __launch_bounds__(256) void pass4_cache(
    const float* __restrict__ a2buf, const float* __restrict__ stats,
    float* __restrict__ outnp) {
  __shared__ float lsc2[128], lsh2[128];
  STAGE256(lsc2, stats + ST_SC2, 128)
  STAGE256(lsh2, stats + ST_SH2, 128)
  __syncthreads();

  const int tid = blockIdx.x * 256 + threadIdx.x;         // == sample
  const int lane = threadIdx.x & 63;
  const int grp = tid >> 5;

#pragma unroll 1
  for (int o = 0; o < 128; o++) {
    const float a = a2buf[(size_t)o * NSAMP + tid];       // coalesced
    float v = fmaxf(fmaf(a, lsc2[o], lsh2[o]), 0.0f);
    v = dpp_max32(v);
    if ((lane & 31) == 31) outnp[(size_t)grp * 128 + o] = v;
  }
}

// ---------------------------------------------------------------------------
extern "C" void kernel_launch(void* const* d_in, const int* in_sizes, int n_in,
                              void* d_out, int out_size, void* d_ws,
                              size_t ws_size, hipStream_t stream) {
  const float* xyz = (const float*)d_in[0];
  const float* points = (const float*)d_in[1];
  const float* w0 = (const float*)d_in[2];
  const float* b0 = (const float*)d_in[3];
  const float* g0 = (const float*)d_in[4];
  const float* be0 = (const float*)d_in[5];
  const float* w1 = (const float*)d_in[6];
  const float* b1 = (const float*)d_in[7];
  const float* g1 = (const float*)d_in[8];
  const float* be1 = (const float*)d_in[9];
  const float* w2 = (const float*)d_in[10];
  const float* b2 = (const float*)d_in[11];
  const float* g2 = (const float*)d_in[12];
  const float* be2 = (const float*)d_in[13];

  float* out = (float*)d_out;
  float* cent = out;                    // (B,P,3)
  float* outnp = out + B * P * 3;       // (B,P,128)

  const size_t GIDX_BYTES = (size_t)NSAMP * sizeof(int);      // 1 MiB
  const size_t STATS_BYTES = 4096;
  const size_t A1_BYTES = (size_t)64 * NSAMP * sizeof(float);   // 64 MiB
  const size_t A2_BYTES = (size_t)128 * NSAMP * sizeof(float);  // 128 MiB
  if (ws_size < GIDX_BYTES + STATS_BYTES) return;             // defensive
  int* gidx = (int*)d_ws;
  float* stats = (float*)((char*)d_ws + GIDX_BYTES);
  float* a1buf = (float*)((char*)d_ws + GIDX_BYTES + STATS_BYTES);
  float* a2buf = a1buf + (size_t)64 * NSAMP;
  const bool cache =
      ws_size >= GIDX_BYTES + STATS_BYTES + A1_BYTES + A2_BYTES;

  hipMemsetAsync(d_ws, 0, GIDX_BYTES + STATS_BYTES, stream);

  fps_kernel<<<B, 512, 0, stream>>>(xyz, cent);
  ballq_kernel<<<(B * P) / 4, 256, 0, stream>>>(xyz, cent, gidx);
  moments_kernel<<<32, 256, 0, stream>>>(xyz, points, cent, gidx, stats);
  finalize0_kernel<<<1, 64, 0, stream>>>(stats, w0, b0, g0, be0);
  if (cache) {
    pass2_t<true><<<NSAMP / 256, 256, 0, stream>>>(
        xyz, points, cent, gidx, w0, b0, w1, b1, stats, a1buf);
    finalize1_kernel<<<1, 64, 0, stream>>>(stats, g1, be1);
    pass3_cache<<<NSAMP / 256, 256, 0, stream>>>(a1buf, w2, b2, stats, a2buf);
    finalize2_kernel<<<1, 128, 0, stream>>>(stats, g2, be2);
    pass4_cache<<<NSAMP / 256, 256, 0, stream>>>(a2buf, stats, outnp);
  } else {
    pass2_t<false><<<NSAMP / 256, 256, 0, stream>>>(
        xyz, points, cent, gidx, w0, b0, w1, b1, stats, a1buf);
    finalize1_kernel<<<1, 64, 0, stream>>>(stats, g1, be1);
    pass3_kernel<<<NSAMP / 256, 256, 0, stream>>>(xyz, points, cent, gidx,
                                                  w0, b0, w1, b1, w2, b2,
                                                  stats);
    finalize2_kernel<<<1, 128, 0, stream>>>(stats, g2, be2);
    pass4_kernel<<<NSAMP / 256, 256, 0, stream>>>(xyz, points, cent, gidx,
                                                  w0, b0, w1, b1, w2, b2,
                                                  stats, outnp);
  }
}